// Round 2
// baseline (1436.708 us; speedup 1.0000x reference)
//
#include <hip/hip_runtime.h>
#include <stdint.h>

// Problem constants
#define B_    32
#define L_    512
#define D_    2048
#define H_    16
#define M_    16384      // B_*L_
#define NQKV_ 6144       // 3*D_
#define TAU_INV 14.285714285714286f
#define LOG2E   1.4426950408889634f
#define SCALE_Q 0.08838834764831845f   // 1/sqrt(128), folded into Wq

using f32x4 = __attribute__((ext_vector_type(4))) float;
using s16x8 = __attribute__((ext_vector_type(8))) short;

__device__ __forceinline__ uint16_t f2bf(float f){
  uint32_t u = __float_as_uint(f);
  uint32_t r = (u + 0x7fffu + ((u >> 16) & 1u)) >> 16;
  return (uint16_t)r;
}

__device__ __forceinline__ void async16(const void* g, void* s){
  __builtin_amdgcn_global_load_lds((const __attribute__((address_space(1))) void*)g,
                                   (__attribute__((address_space(3))) void*)s, 16, 0, 0);
}

// ---------------------------------------------------------------- prep
__global__ void k_prep(const float* __restrict__ sac, const float* __restrict__ s1m,
                       const int* __restrict__ ts, float* __restrict__ scal,
                       double* __restrict__ accs){
  int t = threadIdx.x;
  if (t < 32){ int tt = ts[t]; scal[t] = sac[tt]; scal[32 + t] = s1m[tt]; }
  if (t == 64){ float v = sac[999]; scal[64] = v * v; }
  if (t >= 96 && t < 104) accs[t - 96] = 0.0;
}

// ------------------------------------------- W fp32 [K][N] -> bf16 [N][K] (transposed)
__launch_bounds__(256)
__global__ void k_convw(const float* __restrict__ wq, const float* __restrict__ wk,
                        const float* __restrict__ wv, const float* __restrict__ wo,
                        uint16_t* __restrict__ wqkv_t, uint16_t* __restrict__ wo_t){
  int w = blockIdx.z;
  const float* src = (w == 0) ? wq : (w == 1) ? wk : (w == 2) ? wv : wo;
  uint16_t* dst = (w < 3) ? (wqkv_t + (size_t)w * D_ * D_) : wo_t;
  float scale = (w == 0) ? SCALE_Q : 1.0f;
  __shared__ float tile[64][65];
  int n0 = blockIdx.x * 64, k0 = blockIdx.y * 64;
  int tx = threadIdx.x & 15, ty = threadIdx.x >> 4;
  #pragma unroll
  for (int r = 0; r < 4; r++){
    int kk = ty + r * 16;
    float4 v = *(const float4*)&src[(size_t)(k0 + kk) * D_ + n0 + tx * 4];
    tile[kk][tx*4+0] = v.x; tile[kk][tx*4+1] = v.y;
    tile[kk][tx*4+2] = v.z; tile[kk][tx*4+3] = v.w;
  }
  __syncthreads();
  #pragma unroll
  for (int r = 0; r < 4; r++){
    int nn = ty + r * 16;
    ushort4 o;
    o.x = f2bf(tile[tx*4+0][nn] * scale);
    o.y = f2bf(tile[tx*4+1][nn] * scale);
    o.z = f2bf(tile[tx*4+2][nn] * scale);
    o.w = f2bf(tile[tx*4+3][nn] * scale);
    *(ushort4*)&dst[(size_t)(n0 + nn) * D_ + k0 + tx * 4] = o;
  }
}

// ------------------------- x_t = sa*x_start + s1m*noise (bf16), plus sum(x_start^2)
__launch_bounds__(256)
__global__ void k_xt(const float* __restrict__ seq, const float* __restrict__ lab,
                     const float* __restrict__ noise, const float* __restrict__ scal,
                     double* __restrict__ accs, uint16_t* __restrict__ xt){
  __shared__ float red[4];
  int tid = threadIdx.x;
  size_t base = ((size_t)blockIdx.x * 256 + tid) * 8;
  int b = (int)(base >> 20);
  int rem = (int)(base & 1048575u);
  int l = rem >> 11, d0 = rem & 2047;
  const float* xsp = (l < 256) ? seq + ((size_t)(b * 256 + l) << 11) + d0
                               : lab + ((size_t)(b * 256 + l - 256) << 11) + d0;
  float4 x0 = *(const float4*)xsp;
  float4 x1 = *(const float4*)(xsp + 4);
  float4 n0 = *(const float4*)(noise + base);
  float4 n1 = *(const float4*)(noise + base + 4);
  float sa = scal[b], sm = scal[32 + b];
  ushort4 o0, o1;
  o0.x = f2bf(sa*x0.x + sm*n0.x); o0.y = f2bf(sa*x0.y + sm*n0.y);
  o0.z = f2bf(sa*x0.z + sm*n0.z); o0.w = f2bf(sa*x0.w + sm*n0.w);
  o1.x = f2bf(sa*x1.x + sm*n1.x); o1.y = f2bf(sa*x1.y + sm*n1.y);
  o1.z = f2bf(sa*x1.z + sm*n1.z); o1.w = f2bf(sa*x1.w + sm*n1.w);
  *(ushort4*)(xt + base) = o0;
  *(ushort4*)(xt + base + 4) = o1;
  float s2 = x0.x*x0.x + x0.y*x0.y + x0.z*x0.z + x0.w*x0.w
           + x1.x*x1.x + x1.y*x1.y + x1.z*x1.z + x1.w*x1.w;
  #pragma unroll
  for (int m = 32; m >= 1; m >>= 1){ s2 += __shfl_xor(s2, m); }
  if ((tid & 63) == 0) red[tid >> 6] = s2;
  __syncthreads();
  if (tid == 0) atomicAdd(&accs[0], (double)(red[0] + red[1] + red[2] + red[3]));
}

// ---------------------------------------------------------------- GEMM (m97-style)
// MODE 0: A = x_t [M][K], Bt = Wqkv^T [6144][K]  -> q/k perm [B,H,L,dh], v transposed [B,H,dh,L]
// MODE 1: A = Operm [B,H,L,dh] (addressed), Bt = Wo^T -> fused (xs - mo)^2 reduction
template<int MODE>
__launch_bounds__(256)
__global__ void k_gemm(const uint16_t* __restrict__ A, const uint16_t* __restrict__ Bt,
                       uint16_t* __restrict__ oq, uint16_t* __restrict__ ok,
                       uint16_t* __restrict__ ovt,
                       const float* __restrict__ seq, const float* __restrict__ lab,
                       double* __restrict__ accs){
  __shared__ __align__(16) uint16_t As[128 * 32];
  __shared__ __align__(16) uint16_t Bs[128 * 32];
  __shared__ float red[4];
  const int tid = threadIdx.x;
  const int lane = tid & 63;
  const int wv = tid >> 6, wr = wv >> 1, wc = wv & 1;
  const int r16 = lane & 15, g4 = lane >> 4;
  const int brow = blockIdx.y * 128;
  const int bcol = blockIdx.x * 128;
  // staging slots: slot s -> row = s>>2, part = s&3; part XOR-swizzled by (row&3)
  const int rowA0 = tid >> 2, p0 = tid & 3;
  const int rowA1 = rowA0 + 64;
  const int sw0 = (p0 ^ (rowA0 & 3)) * 8;
  const int sw1 = (p0 ^ (rowA1 & 3)) * 8;
  const int swr = (g4 ^ (r16 & 3)) * 8;   // read-side: same involution

  const f32x4 z4 = {0.f, 0.f, 0.f, 0.f};
  f32x4 acc[4][4];
  #pragma unroll
  for (int i = 0; i < 4; i++){
    #pragma unroll
    for (int j = 0; j < 4; j++){ acc[i][j] = z4; }
  }

  for (int k0 = 0; k0 < 2048; k0 += 32){
    if (MODE == 0){
      async16(A + (size_t)(brow + rowA0) * 2048 + k0 + sw0, &As[rowA0 * 32 + p0 * 8]);
      async16(A + (size_t)(brow + rowA1) * 2048 + k0 + sw1, &As[rowA1 * 32 + p0 * 8]);
    } else {
      const int hh = k0 >> 7, dhb = k0 & 127;
      const int m0 = brow + rowA0, m1 = brow + rowA1;
      async16(A + (size_t)(((m0 >> 9) * 16 + hh) * 512 + (m0 & 511)) * 128 + dhb + sw0,
              &As[rowA0 * 32 + p0 * 8]);
      async16(A + (size_t)(((m1 >> 9) * 16 + hh) * 512 + (m1 & 511)) * 128 + dhb + sw1,
              &As[rowA1 * 32 + p0 * 8]);
    }
    async16(Bt + (size_t)(bcol + rowA0) * 2048 + k0 + sw0, &Bs[rowA0 * 32 + p0 * 8]);
    async16(Bt + (size_t)(bcol + rowA1) * 2048 + k0 + sw1, &Bs[rowA1 * 32 + p0 * 8]);
    __syncthreads();
    s16x8 af[4], bfr[4];
    #pragma unroll
    for (int i = 0; i < 4; i++){
      af[i] = *(const s16x8*)&As[(wr * 64 + i * 16 + r16) * 32 + swr];
    }
    #pragma unroll
    for (int j = 0; j < 4; j++){
      bfr[j] = *(const s16x8*)&Bs[(wc * 64 + j * 16 + r16) * 32 + swr];
    }
    #pragma unroll
    for (int i = 0; i < 4; i++){
      #pragma unroll
      for (int j = 0; j < 4; j++){
        acc[i][j] = __builtin_amdgcn_mfma_f32_16x16x32_bf16(af[i], bfr[j], acc[i][j], 0, 0, 0);
      }
    }
    __syncthreads();
  }

  if (MODE == 0){
    #pragma unroll
    for (int i = 0; i < 4; i++){
      const int m = brow + wr * 64 + i * 16 + g4 * 4;
      const int bb = m >> 9, lbase = m & 511;
      #pragma unroll
      for (int j = 0; j < 4; j++){
        const int n = bcol + wc * 64 + j * 16 + r16;
        const int which = n >> 11, nn = n & 2047;
        const int hh = nn >> 7, dh = nn & 127;
        if (which == 2){
          ushort4 ov;
          ov.x = f2bf(acc[i][j][0]); ov.y = f2bf(acc[i][j][1]);
          ov.z = f2bf(acc[i][j][2]); ov.w = f2bf(acc[i][j][3]);
          *(ushort4*)&ovt[((size_t)((bb * 16 + hh) * 128 + dh)) * 512 + lbase] = ov;
        } else {
          uint16_t* dst = (which == 0) ? oq : ok;
          #pragma unroll
          for (int r = 0; r < 4; r++){
            dst[((size_t)((bb * 16 + hh) * 512 + lbase + r)) * 128 + dh] = f2bf(acc[i][j][r]);
          }
        }
      }
    }
  } else {
    float msum = 0.f;
    #pragma unroll
    for (int i = 0; i < 4; i++){
      const int m = brow + wr * 64 + i * 16 + g4 * 4;
      const int bb = m >> 9;
      #pragma unroll
      for (int j = 0; j < 4; j++){
        const int n = bcol + wc * 64 + j * 16 + r16;
        #pragma unroll
        for (int r = 0; r < 4; r++){
          const int l = (m + r) & 511;
          const float xs = (l < 256)
              ? seq[((size_t)(bb * 256 + l)) * 2048 + n]
              : lab[((size_t)(bb * 256 + l - 256)) * 2048 + n];
          const float d = xs - acc[i][j][r];
          msum += d * d;
        }
      }
    }
    #pragma unroll
    for (int s = 32; s >= 1; s >>= 1){ msum += __shfl_xor(msum, s); }
    if (lane == 0) red[wv] = msum;
    __syncthreads();
    if (tid == 0) atomicAdd(&accs[1], (double)(red[0] + red[1] + red[2] + red[3]));
  }
}

// ---------------------------------------------------------------- flash attention
// grid = B*H*4, block = 256 (4 waves x 32 q-rows). K tiles of 64; V pre-transposed.
__launch_bounds__(256)
__global__ void k_attn(const uint16_t* __restrict__ q, const uint16_t* __restrict__ kk,
                       const uint16_t* __restrict__ vt, uint16_t* __restrict__ o){
  __shared__ __align__(16) uint16_t Ks[64 * 128];   // [kv][dh], part^=(row&7)
  __shared__ __align__(16) uint16_t Vs[128 * 64];   // [dh][kv], part^=(row&7)
  __shared__ __align__(16) uint16_t Ps[4][32][72];  // per-wave P, padded stride 72
  const int tid = threadIdx.x, lane = tid & 63, wv = tid >> 6;
  const int r16 = lane & 15, g4 = lane >> 4;
  const int bid = blockIdx.x;
  const int qb = bid & 3, hh = (bid >> 2) & 15, bb = bid >> 6;
  const size_t head = (size_t)(bb * 16 + hh) * 512 * 128;
  const int q0 = qb * 128 + wv * 32;

  const f32x4 z4 = {0.f, 0.f, 0.f, 0.f};
  s16x8 aq[2][4];
  #pragma unroll
  for (int mi = 0; mi < 2; mi++){
    #pragma unroll
    for (int kb = 0; kb < 4; kb++){
      aq[mi][kb] = *(const s16x8*)&q[head + (size_t)(q0 + mi * 16 + r16) * 128 + kb * 32 + g4 * 8];
    }
  }
  f32x4 oacc[2][8];
  #pragma unroll
  for (int mi = 0; mi < 2; mi++){
    #pragma unroll
    for (int nf = 0; nf < 8; nf++){ oacc[mi][nf] = z4; }
  }
  f32x4 mrun[2], lrun[2];
  const f32x4 minit = {-1e30f, -1e30f, -1e30f, -1e30f};
  mrun[0] = minit; mrun[1] = minit; lrun[0] = z4; lrun[1] = z4;

  for (int t = 0; t < 8; t++){
    const int kv0 = t * 64;
    #pragma unroll
    for (int it = 0; it < 4; it++){
      const int s = it * 256 + tid;
      const int row = s >> 4, p = s & 15;
      const int pg = p ^ (row & 7);
      async16(kk + head + (size_t)(kv0 + row) * 128 + pg * 8, &Ks[s * 8]);
    }
    #pragma unroll
    for (int it = 0; it < 4; it++){
      const int s = it * 256 + tid;
      const int row = s >> 3, p = s & 7;
      const int pg = p ^ (row & 7);
      async16(vt + head + (size_t)row * 512 + kv0 + pg * 8, &Vs[s * 8]);
    }
    __syncthreads();

    f32x4 sf[2][4];
    #pragma unroll
    for (int mi = 0; mi < 2; mi++){
      #pragma unroll
      for (int nj = 0; nj < 4; nj++){ sf[mi][nj] = z4; }
    }
    #pragma unroll
    for (int kb = 0; kb < 4; kb++){
      #pragma unroll
      for (int nj = 0; nj < 4; nj++){
        const int krow = nj * 16 + r16;
        const s16x8 bk = *(const s16x8*)&Ks[krow * 128 + (((kb * 4 + g4) ^ (krow & 7)) * 8)];
        sf[0][nj] = __builtin_amdgcn_mfma_f32_16x16x32_bf16(aq[0][kb], bk, sf[0][nj], 0, 0, 0);
        sf[1][nj] = __builtin_amdgcn_mfma_f32_16x16x32_bf16(aq[1][kb], bk, sf[1][nj], 0, 0, 0);
      }
    }
    #pragma unroll
    for (int mi = 0; mi < 2; mi++){
      float sc[4];
      #pragma unroll
      for (int r = 0; r < 4; r++){
        float v = fmaxf(fmaxf(sf[mi][0][r], sf[mi][1][r]), fmaxf(sf[mi][2][r], sf[mi][3][r]));
        v = fmaxf(v, __shfl_xor(v, 1));
        v = fmaxf(v, __shfl_xor(v, 2));
        v = fmaxf(v, __shfl_xor(v, 4));
        v = fmaxf(v, __shfl_xor(v, 8));
        const float mold = mrun[mi][r];
        const float mnew = fmaxf(mold, v);
        sc[r] = exp2f((mold - mnew) * LOG2E);
        mrun[mi][r] = mnew;
      }
      float ps[4] = {0.f, 0.f, 0.f, 0.f};
      #pragma unroll
      for (int nj = 0; nj < 4; nj++){
        #pragma unroll
        for (int r = 0; r < 4; r++){
          const float p = exp2f((sf[mi][nj][r] - mrun[mi][r]) * LOG2E);
          ps[r] += p;
          Ps[wv][mi * 16 + g4 * 4 + r][nj * 16 + r16] = f2bf(p);
        }
      }
      #pragma unroll
      for (int r = 0; r < 4; r++){
        float v = ps[r];
        v += __shfl_xor(v, 1); v += __shfl_xor(v, 2);
        v += __shfl_xor(v, 4); v += __shfl_xor(v, 8);
        lrun[mi][r] = lrun[mi][r] * sc[r] + v;
      }
      #pragma unroll
      for (int nf = 0; nf < 8; nf++){
        #pragma unroll
        for (int r = 0; r < 4; r++){ oacc[mi][nf][r] *= sc[r]; }
      }
    }
    // PV
    #pragma unroll
    for (int kc = 0; kc < 2; kc++){
      const s16x8 ap0 = *(const s16x8*)&Ps[wv][r16][kc * 32 + g4 * 8];
      const s16x8 ap1 = *(const s16x8*)&Ps[wv][16 + r16][kc * 32 + g4 * 8];
      #pragma unroll
      for (int nf = 0; nf < 8; nf++){
        const int dh = nf * 16 + r16;
        const s16x8 bv = *(const s16x8*)&Vs[dh * 64 + (((kc * 4 + g4) ^ (dh & 7)) * 8)];
        oacc[0][nf] = __builtin_amdgcn_mfma_f32_16x16x32_bf16(ap0, bv, oacc[0][nf], 0, 0, 0);
        oacc[1][nf] = __builtin_amdgcn_mfma_f32_16x16x32_bf16(ap1, bv, oacc[1][nf], 0, 0, 0);
      }
    }
    __syncthreads();
  }
  #pragma unroll
  for (int mi = 0; mi < 2; mi++){
    #pragma unroll
    for (int r = 0; r < 4; r++){
      const float inv = 1.0f / lrun[mi][r];
      const size_t rowbase = head + (size_t)(q0 + mi * 16 + g4 * 4 + r) * 128;
      #pragma unroll
      for (int nf = 0; nf < 8; nf++){
        o[rowbase + nf * 16 + r16] = f2bf(oacc[mi][nf][r] * inv);
      }
    }
  }
}

// ------------------------- per-channel contrastive: gram + norms + lse, fully fused
__launch_bounds__(256)
__global__ void k_contrast(const float* __restrict__ seq, const float* __restrict__ lab,
                           double* __restrict__ accs){
  __shared__ float ss[8][32][8];
  __shared__ float ls[8][32][8];
  __shared__ float rsl[32][8];
  __shared__ float redM[4], redC[4];
  const int tid = threadIdx.x, lane = tid & 63, wv = tid >> 6;
  const int i = tid >> 3, dd = tid & 7;
  const int d = blockIdx.x * 8 + dd;
  float accM[32], accC[32];
  #pragma unroll
  for (int j = 0; j < 32; j++){ accM[j] = 0.f; accC[j] = 0.f; }
  float accS = 0.f, accL = 0.f;
  for (int l0 = 0; l0 < 256; l0 += 8){
    #pragma unroll
    for (int li = 0; li < 8; li++){
      ss[li][i][dd] = seq[((size_t)(i * 256 + l0 + li)) * 2048 + d];
      ls[li][i][dd] = lab[((size_t)(i * 256 + l0 + li)) * 2048 + d];
    }
    __syncthreads();
    #pragma unroll
    for (int li = 0; li < 8; li++){
      const float sv = ss[li][i][dd];
      const float lv = ls[li][i][dd];
      accS += sv * sv; accL += lv * lv;
      #pragma unroll
      for (int j = 0; j < 32; j++){
        const float lj = ls[li][j][dd];
        accM[j] += sv * lj;
        accC[j] += lv * lj;
      }
    }
    __syncthreads();
  }
  rsl[i][dd] = rsqrtf(accL);
  __syncthreads();
  const float rs1 = rsqrtf(accS);
  const float rso = rsl[i][dd];
  // match loss: two passes (no runtime-indexed array)
  float mx = -1e30f, diag = 0.f;
  #pragma unroll
  for (int j = 0; j < 32; j++){
    const float lg = accM[j] * rs1 * rsl[j][dd] * TAU_INV;
    mx = fmaxf(mx, lg);
    if (j == i) diag = lg;
  }
  float sum = 0.f;
  #pragma unroll
  for (int j = 0; j < 32; j++){
    const float lg = accM[j] * rs1 * rsl[j][dd] * TAU_INV;
    sum += exp2f((lg - mx) * LOG2E);
  }
  const float lossM = mx + logf(sum) - diag;
  // ctr loss
  mx = -1e30f; diag = 0.f;
  #pragma unroll
  for (int j = 0; j < 32; j++){
    const float lg = accC[j] * rso * rsl[j][dd] * TAU_INV;
    mx = fmaxf(mx, lg);
    if (j == i) diag = lg;
  }
  sum = 0.f;
  #pragma unroll
  for (int j = 0; j < 32; j++){
    const float lg = accC[j] * rso * rsl[j][dd] * TAU_INV;
    sum += exp2f((lg - mx) * LOG2E);
  }
  const float lossC = mx + logf(sum) - diag;

  float vM = lossM, vC = lossC;
  #pragma unroll
  for (int s = 32; s >= 1; s >>= 1){ vM += __shfl_xor(vM, s); vC += __shfl_xor(vC, s); }
  if (lane == 0){ redM[wv] = vM; redC[wv] = vC; }
  __syncthreads();
  if (tid == 0){
    atomicAdd(&accs[2], (double)(redM[0] + redM[1] + redM[2] + redM[3]));
    atomicAdd(&accs[3], (double)(redC[0] + redC[1] + redC[2] + redC[3]));
  }
}

// ---------------------------------------------------------------- finalize
__global__ void k_final(const float* __restrict__ scal, const double* __restrict__ accs,
                        float* __restrict__ out){
  if (threadIdx.x == 0){
    const double inv = 1.0 / ((double)M_ * (double)D_);
    double v = accs[1] * inv                      // mse
             + (double)scal[64] * accs[0] * inv   // tT
             + accs[2] / 65536.0                  // match
             + accs[3] / 65536.0;                 // ctr
    out[0] = (float)v;
  }
}

extern "C" void kernel_launch(void* const* d_in, const int* in_sizes, int n_in,
                              void* d_out, int out_size, void* d_ws, size_t ws_size,
                              hipStream_t stream){
  const float* seq   = (const float*)d_in[0];
  const float* lab   = (const float*)d_in[1];
  const float* noise = (const float*)d_in[2];
  const float* sac   = (const float*)d_in[3];
  const float* s1m   = (const float*)d_in[4];
  const float* wq    = (const float*)d_in[5];
  const float* wk    = (const float*)d_in[6];
  const float* wvp   = (const float*)d_in[7];
  const float* wo    = (const float*)d_in[8];
  const int*   ts    = (const int*)d_in[9];

  char* ws = (char*)d_ws;
  float*    scal = (float*)ws;                         // 512 B
  double*   accs = (double*)(ws + 512);                // 64 B
  uint16_t* wqkv = (uint16_t*)(ws + 1024);             // [6144][2048] bf16
  uint16_t* wo_t = wqkv + (size_t)NQKV_ * D_;          // [2048][2048] bf16
  uint16_t* xt   = wo_t + (size_t)D_ * D_;             // [M][D] bf16, later reused as Operm
  uint16_t* qb   = xt + (size_t)M_ * D_;               // [B,H,512,128] bf16
  uint16_t* kb   = qb + (size_t)M_ * D_;
  uint16_t* vtb  = kb + (size_t)M_ * D_;               // [B,H,128,512] bf16 (transposed)
  float* out = (float*)d_out;

  k_prep<<<1, 128, 0, stream>>>(sac, s1m, ts, scal, accs);
  k_convw<<<dim3(32, 32, 4), 256, 0, stream>>>(wq, wk, wvp, wo, wqkv, wo_t);
  k_xt<<<16384, 256, 0, stream>>>(seq, lab, noise, scal, accs, xt);
  k_gemm<0><<<dim3(48, 128), 256, 0, stream>>>(xt, wqkv, qb, kb, vtb, nullptr, nullptr, nullptr);
  k_attn<<<2048, 256, 0, stream>>>(qb, kb, vtb, xt);  // writes Operm into xt buffer
  k_gemm<1><<<dim3(16, 128), 256, 0, stream>>>(xt, wo_t, nullptr, nullptr, nullptr, seq, lab, accs);
  k_contrast<<<256, 256, 0, stream>>>(seq, lab, accs);
  k_final<<<1, 64, 0, stream>>>(scal, accs, out);
}

// Round 3
// 1352.858 us; speedup vs baseline: 1.0620x; 1.0620x over previous
//
#include <hip/hip_runtime.h>
#include <stdint.h>

#define B_    32
#define L_    512
#define D_    2048
#define H_    16
#define M_    16384
#define NQKV_ 6144
#define TAU_INV 14.285714285714286f
#define LOG2E   1.4426950408889634f
#define SCALE_Q 0.08838834764831845f

using f32x4 = __attribute__((ext_vector_type(4))) float;
using s16x8 = __attribute__((ext_vector_type(8))) short;

__device__ __forceinline__ uint16_t f2bf(float f){
  uint32_t u = __float_as_uint(f);
  uint32_t r = (u + 0x7fffu + ((u >> 16) & 1u)) >> 16;
  return (uint16_t)r;
}

__device__ __forceinline__ void async16(const void* g, void* s){
  __builtin_amdgcn_global_load_lds((const __attribute__((address_space(1))) void*)g,
                                   (__attribute__((address_space(3))) void*)s, 16, 0, 0);
}

// ---------------------------------------------------------------- prep
__global__ void k_prep(const float* __restrict__ sac, const float* __restrict__ s1m,
                       const int* __restrict__ ts, float* __restrict__ scal,
                       double* __restrict__ accs){
  int t = threadIdx.x;
  if (t < 32){ int tt = ts[t]; scal[t] = sac[tt]; scal[32 + t] = s1m[tt]; }
  if (t == 64){ float v = sac[999]; scal[64] = v * v; }
  if (t >= 96 && t < 104) accs[t - 96] = 0.0;
}

// ------------------------------------------- W fp32 [K][N] -> bf16 [N][K]
__launch_bounds__(256)
__global__ void k_convw(const float* __restrict__ wq, const float* __restrict__ wk,
                        const float* __restrict__ wv, const float* __restrict__ wo,
                        uint16_t* __restrict__ wqkv_t, uint16_t* __restrict__ wo_t){
  int w = blockIdx.z;
  const float* src = (w == 0) ? wq : (w == 1) ? wk : (w == 2) ? wv : wo;
  uint16_t* dst = (w < 3) ? (wqkv_t + (size_t)w * D_ * D_) : wo_t;
  float scale = (w == 0) ? SCALE_Q : 1.0f;
  __shared__ float tile[64][65];
  int n0 = blockIdx.x * 64, k0 = blockIdx.y * 64;
  int tx = threadIdx.x & 15, ty = threadIdx.x >> 4;
  #pragma unroll
  for (int r = 0; r < 4; r++){
    int kk = ty + r * 16;
    float4 v = *(const float4*)&src[(size_t)(k0 + kk) * D_ + n0 + tx * 4];
    tile[kk][tx*4+0] = v.x; tile[kk][tx*4+1] = v.y;
    tile[kk][tx*4+2] = v.z; tile[kk][tx*4+3] = v.w;
  }
  __syncthreads();
  #pragma unroll
  for (int r = 0; r < 4; r++){
    int nn = ty + r * 16;
    ushort4 o;
    o.x = f2bf(tile[tx*4+0][nn] * scale);
    o.y = f2bf(tile[tx*4+1][nn] * scale);
    o.z = f2bf(tile[tx*4+2][nn] * scale);
    o.w = f2bf(tile[tx*4+3][nn] * scale);
    *(ushort4*)&dst[(size_t)(n0 + nn) * D_ + k0 + tx * 4] = o;
  }
}

// ------------------------- x_t = sa*x_start + s1m*noise (bf16) + sum(x_start^2)
__launch_bounds__(256)
__global__ void k_xt(const float* __restrict__ seq, const float* __restrict__ lab,
                     const float* __restrict__ noise, const float* __restrict__ scal,
                     double* __restrict__ accs, uint16_t* __restrict__ xt){
  __shared__ float red[4];
  int tid = threadIdx.x;
  size_t base = ((size_t)blockIdx.x * 256 + tid) * 8;
  int b = (int)(base >> 20);
  int rem = (int)(base & 1048575u);
  int l = rem >> 11, d0 = rem & 2047;
  const float* xsp = (l < 256) ? seq + ((size_t)(b * 256 + l) << 11) + d0
                               : lab + ((size_t)(b * 256 + l - 256) << 11) + d0;
  float4 x0 = *(const float4*)xsp;
  float4 x1 = *(const float4*)(xsp + 4);
  float4 n0 = *(const float4*)(noise + base);
  float4 n1 = *(const float4*)(noise + base + 4);
  float sa = scal[b], sm = scal[32 + b];
  ushort4 o0, o1;
  o0.x = f2bf(sa*x0.x + sm*n0.x); o0.y = f2bf(sa*x0.y + sm*n0.y);
  o0.z = f2bf(sa*x0.z + sm*n0.z); o0.w = f2bf(sa*x0.w + sm*n0.w);
  o1.x = f2bf(sa*x1.x + sm*n1.x); o1.y = f2bf(sa*x1.y + sm*n1.y);
  o1.z = f2bf(sa*x1.z + sm*n1.z); o1.w = f2bf(sa*x1.w + sm*n1.w);
  *(ushort4*)(xt + base) = o0;
  *(ushort4*)(xt + base + 4) = o1;
  float s2 = x0.x*x0.x + x0.y*x0.y + x0.z*x0.z + x0.w*x0.w
           + x1.x*x1.x + x1.y*x1.y + x1.z*x1.z + x1.w*x1.w;
  #pragma unroll
  for (int m = 32; m >= 1; m >>= 1){ s2 += __shfl_xor(s2, m); }
  if ((tid & 63) == 0) red[tid >> 6] = s2;
  __syncthreads();
  if (tid == 0) atomicAdd(&accs[0], (double)(red[0] + red[1] + red[2] + red[3]));
}

// ------------------- 256x256 8-phase GEMM (T2+T3+T4+T5), BK=64, 512 threads
// MODE 0: A=x_t[M][K], Bt=Wqkv^T -> q/k perm [B,H,512,128], v^T [B,H,128,512]
// MODE 1: A=Operm [B,H,512,128], Bt=Wo^T -> fused (xs-mo)^2 reduction
template<int MODE>
__launch_bounds__(512, 2)
__global__ void k_gemm256(const uint16_t* __restrict__ A, const uint16_t* __restrict__ Bt,
                          uint16_t* __restrict__ oq, uint16_t* __restrict__ ok,
                          uint16_t* __restrict__ ovt,
                          const float* __restrict__ seq, const float* __restrict__ lab,
                          double* __restrict__ accs){
  // lds[buf][half]: half 0=A-ks0, 1=B-ks0, 2=A-ks1, 3=B-ks1; each 256 rows x 32 K
  __shared__ __align__(16) uint16_t lds[2][4][256 * 32];
  __shared__ float red[8];
  const int tid = threadIdx.x, lane = tid & 63, wid = tid >> 6;
  const int wr = wid >> 2, wc = wid & 3;
  const int r16 = lane & 15, g4 = lane >> 4;
  const int NX = (MODE == 0) ? 24 : 8;
  const int nwg = (MODE == 0) ? 1536 : 512;
  const int id = blockIdx.x;
  const int wgs = (id & 7) * (nwg >> 3) + (id >> 3);   // XCD-aware swizzle (nwg%8==0)
  const int by = wgs / NX, bx = wgs % NX;
  const int brow = by * 256, bcol = bx * 256;

  // staging precompute: issue i covers slots s=i*512+tid -> row=s>>2, slot=s&3
  int srow[2], gp8[2], dstoff[2];
  #pragma unroll
  for (int i = 0; i < 2; i++){
    int s = i * 512 + tid;
    srow[i] = s >> 2;
    gp8[i] = (((s & 3) ^ ((srow[i] >> 1) & 3)) << 3);  // source K-part (pre-swizzled)
    dstoff[i] = s * 8;                                  // linear LDS dest (elements)
  }

  auto stageA = [&](int t, int s, int b){
    #pragma unroll
    for (int i = 0; i < 2; i++){
      const uint16_t* src;
      if (MODE == 0){
        src = A + (size_t)(brow + srow[i]) * 2048 + t * 64 + s * 32 + gp8[i];
      } else {
        int m = brow + srow[i];
        src = A + (size_t)(((m >> 9) * 16 + (t >> 1)) * 512 + (m & 511)) * 128
                + (t & 1) * 64 + s * 32 + gp8[i];
      }
      async16(src, &lds[b][2 * s][dstoff[i]]);
    }
  };
  auto stageB = [&](int t, int s, int b){
    #pragma unroll
    for (int i = 0; i < 2; i++){
      async16(Bt + (size_t)(bcol + srow[i]) * 2048 + t * 64 + s * 32 + gp8[i],
              &lds[b][2 * s + 1][dstoff[i]]);
    }
  };

  // fragment read offsets (swizzle reduces to rsw since rows are 0 mod 8 apart)
  const int rsw = (r16 >> 1) & 3;
  int aoff[8], boff[4];
  #pragma unroll
  for (int mf = 0; mf < 8; mf++){
    aoff[mf] = (wr * 128 + mf * 16 + r16) * 32 + ((g4 ^ rsw) << 3);
  }
  #pragma unroll
  for (int nf = 0; nf < 4; nf++){
    boff[nf] = (wc * 64 + nf * 16 + r16) * 32 + ((g4 ^ rsw) << 3);
  }

  const f32x4 z4 = {0.f, 0.f, 0.f, 0.f};
  f32x4 acc[8][4];
  #pragma unroll
  for (int i = 0; i < 8; i++){
    #pragma unroll
    for (int j = 0; j < 4; j++){ acc[i][j] = z4; }
  }

  // prologue: stage tile 0 fully [A0,B0,A1,B1]; drain first half-pair
  stageA(0, 0, 0); stageB(0, 0, 0); stageA(0, 1, 0); stageB(0, 1, 0);
  asm volatile("s_waitcnt vmcnt(4)" ::: "memory");
  __builtin_amdgcn_s_barrier();

  for (int t = 0; t < 32; t++){
    const int c = t & 1, nb = c ^ 1, tn = (t + 1) & 31;  // t=31 stages dummy (tile 0)
    #pragma unroll
    for (int s = 0; s < 2; s++){
      // phase (s,0): B frags + A frags mf0-3, stage next tile's A-half s
      s16x8 bfrag[4], afrag[4];
      #pragma unroll
      for (int nf = 0; nf < 4; nf++) bfrag[nf] = *(const s16x8*)&lds[c][2*s+1][boff[nf]];
      #pragma unroll
      for (int mf = 0; mf < 4; mf++) afrag[mf] = *(const s16x8*)&lds[c][2*s][aoff[mf]];
      stageA(tn, s, nb);
      __builtin_amdgcn_s_setprio(1);
      #pragma unroll
      for (int mf = 0; mf < 4; mf++){
        #pragma unroll
        for (int nf = 0; nf < 4; nf++){
          acc[mf][nf] = __builtin_amdgcn_mfma_f32_16x16x32_bf16(afrag[mf], bfrag[nf], acc[mf][nf], 0, 0, 0);
        }
      }
      __builtin_amdgcn_s_setprio(0);
      __builtin_amdgcn_s_barrier();
      // phase (s,1): A frags mf4-7 (B reused), stage next tile's B-half s, counted wait
      #pragma unroll
      for (int mf = 0; mf < 4; mf++) afrag[mf] = *(const s16x8*)&lds[c][2*s][aoff[4+mf]];
      stageB(tn, s, nb);
      asm volatile("s_waitcnt vmcnt(4)" ::: "memory");
      __builtin_amdgcn_s_setprio(1);
      #pragma unroll
      for (int mf = 0; mf < 4; mf++){
        #pragma unroll
        for (int nf = 0; nf < 4; nf++){
          acc[4+mf][nf] = __builtin_amdgcn_mfma_f32_16x16x32_bf16(afrag[mf], bfrag[nf], acc[4+mf][nf], 0, 0, 0);
        }
      }
      __builtin_amdgcn_s_setprio(0);
      __builtin_amdgcn_s_barrier();
    }
  }

  if (MODE == 0){
    #pragma unroll
    for (int mf = 0; mf < 8; mf++){
      const int m = brow + wr * 128 + mf * 16 + g4 * 4;
      const int bb = m >> 9, lbase = m & 511;
      #pragma unroll
      for (int nf = 0; nf < 4; nf++){
        const int n = bcol + wc * 64 + nf * 16 + r16;
        const int which = n >> 11, nn = n & 2047;
        const int hh = nn >> 7, dh = nn & 127;
        if (which == 2){
          ushort4 ov;
          ov.x = f2bf(acc[mf][nf][0]); ov.y = f2bf(acc[mf][nf][1]);
          ov.z = f2bf(acc[mf][nf][2]); ov.w = f2bf(acc[mf][nf][3]);
          *(ushort4*)&ovt[((size_t)((bb * 16 + hh) * 128 + dh)) * 512 + lbase] = ov;
        } else {
          uint16_t* dst = (which == 0) ? oq : ok;
          #pragma unroll
          for (int r = 0; r < 4; r++){
            dst[((size_t)((bb * 16 + hh) * 512 + lbase + r)) * 128 + dh] = f2bf(acc[mf][nf][r]);
          }
        }
      }
    }
  } else {
    float msum = 0.f;
    #pragma unroll
    for (int mf = 0; mf < 8; mf++){
      const int m = brow + wr * 128 + mf * 16 + g4 * 4;
      const int bb = m >> 9;
      #pragma unroll
      for (int nf = 0; nf < 4; nf++){
        const int n = bcol + wc * 64 + nf * 16 + r16;
        #pragma unroll
        for (int r = 0; r < 4; r++){
          const int l = (m + r) & 511;
          const float xs = (l < 256)
              ? seq[((size_t)(bb * 256 + l)) * 2048 + n]
              : lab[((size_t)(bb * 256 + l - 256)) * 2048 + n];
          const float d = xs - acc[mf][nf][r];
          msum += d * d;
        }
      }
    }
    #pragma unroll
    for (int sh = 32; sh >= 1; sh >>= 1){ msum += __shfl_xor(msum, sh); }
    if (lane == 0) red[wid] = msum;
    __syncthreads();
    if (tid == 0){
      float tot = 0.f;
      #pragma unroll
      for (int i = 0; i < 8; i++) tot += red[i];
      atomicAdd(&accs[1], (double)tot);
    }
  }
}

// -------------- flash attention: KVB=32, double-buffered, counted vmcnt
// grid = B*H*4, block = 256 (4 waves x 32 q-rows)
__launch_bounds__(256)
__global__ void k_attn(const uint16_t* __restrict__ q, const uint16_t* __restrict__ kk,
                       const uint16_t* __restrict__ vt, uint16_t* __restrict__ o){
  __shared__ __align__(16) uint16_t Ks[2][32 * 128];  // [kv][dh], 16 parts, p^=(row&7)
  __shared__ __align__(16) uint16_t Vs[2][128 * 32];  // [dh][kv], 4 parts, p^=((row>>1)&3)
  __shared__ __align__(16) uint16_t Ps[4][32][72];    // per-wave P, stride 72
  const int tid = threadIdx.x, lane = tid & 63, wv = tid >> 6;
  const int r16 = lane & 15, g4 = lane >> 4;
  const int bid = blockIdx.x;
  const int qb = bid & 3, hh = (bid >> 2) & 15, bb = bid >> 6;
  const size_t head = (size_t)(bb * 16 + hh) * 512 * 128;
  const int q0 = qb * 128 + wv * 32;

  const f32x4 z4 = {0.f, 0.f, 0.f, 0.f};
  s16x8 aq[2][4];
  #pragma unroll
  for (int mi = 0; mi < 2; mi++){
    #pragma unroll
    for (int kb = 0; kb < 4; kb++){
      aq[mi][kb] = *(const s16x8*)&q[head + (size_t)(q0 + mi * 16 + r16) * 128 + kb * 32 + g4 * 8];
    }
  }
  f32x4 oacc[2][8];
  #pragma unroll
  for (int mi = 0; mi < 2; mi++){
    #pragma unroll
    for (int nf = 0; nf < 8; nf++){ oacc[mi][nf] = z4; }
  }
  f32x4 mrun[2], lrun[2];
  const f32x4 minit = {-1e30f, -1e30f, -1e30f, -1e30f};
  mrun[0] = minit; mrun[1] = minit; lrun[0] = z4; lrun[1] = z4;

  auto stageKV = [&](int t, int b){
    const int kv0 = t * 32;
    #pragma unroll
    for (int it = 0; it < 2; it++){
      int s = it * 256 + tid;
      int row = s >> 4, p = s & 15;
      async16(kk + head + (size_t)(kv0 + row) * 128 + ((p ^ (row & 7)) << 3), &Ks[b][s * 8]);
    }
    #pragma unroll
    for (int it = 0; it < 2; it++){
      int s = it * 256 + tid;
      int row = s >> 2, p = s & 3;
      async16(vt + head + (size_t)row * 512 + kv0 + ((p ^ ((row >> 1) & 3)) << 3), &Vs[b][s * 8]);
    }
  };

  stageKV(0, 0);
  for (int t = 0; t < 16; t++){
    const int c = t & 1;
    if (t < 15){
      stageKV(t + 1, c ^ 1);
      asm volatile("s_waitcnt vmcnt(4)" ::: "memory");
    } else {
      asm volatile("s_waitcnt vmcnt(0)" ::: "memory");
    }
    __builtin_amdgcn_s_barrier();

    f32x4 sf[2][2];
    sf[0][0] = z4; sf[0][1] = z4; sf[1][0] = z4; sf[1][1] = z4;
    #pragma unroll
    for (int kb = 0; kb < 4; kb++){
      #pragma unroll
      for (int nj = 0; nj < 2; nj++){
        const int krow = nj * 16 + r16;
        const s16x8 bk = *(const s16x8*)&Ks[c][krow * 128 + ((((kb * 4 + g4) ^ (krow & 7))) << 3)];
        sf[0][nj] = __builtin_amdgcn_mfma_f32_16x16x32_bf16(aq[0][kb], bk, sf[0][nj], 0, 0, 0);
        sf[1][nj] = __builtin_amdgcn_mfma_f32_16x16x32_bf16(aq[1][kb], bk, sf[1][nj], 0, 0, 0);
      }
    }
    #pragma unroll
    for (int mi = 0; mi < 2; mi++){
      float sc[4];
      #pragma unroll
      for (int r = 0; r < 4; r++){
        float v = fmaxf(sf[mi][0][r], sf[mi][1][r]);
        v = fmaxf(v, __shfl_xor(v, 1));
        v = fmaxf(v, __shfl_xor(v, 2));
        v = fmaxf(v, __shfl_xor(v, 4));
        v = fmaxf(v, __shfl_xor(v, 8));
        const float mold = mrun[mi][r];
        const float mnew = fmaxf(mold, v);
        sc[r] = exp2f((mold - mnew) * LOG2E);
        mrun[mi][r] = mnew;
      }
      float ps[4] = {0.f, 0.f, 0.f, 0.f};
      #pragma unroll
      for (int nj = 0; nj < 2; nj++){
        #pragma unroll
        for (int r = 0; r < 4; r++){
          const float p = exp2f((sf[mi][nj][r] - mrun[mi][r]) * LOG2E);
          ps[r] += p;
          Ps[wv][mi * 16 + g4 * 4 + r][nj * 16 + r16] = f2bf(p);
        }
      }
      #pragma unroll
      for (int r = 0; r < 4; r++){
        float v = ps[r];
        v += __shfl_xor(v, 1); v += __shfl_xor(v, 2);
        v += __shfl_xor(v, 4); v += __shfl_xor(v, 8);
        lrun[mi][r] = lrun[mi][r] * sc[r] + v;
      }
      #pragma unroll
      for (int nf = 0; nf < 8; nf++){
        #pragma unroll
        for (int r = 0; r < 4; r++){ oacc[mi][nf][r] *= sc[r]; }
      }
    }
    // PV (single K-step of 32)
    const s16x8 ap0 = *(const s16x8*)&Ps[wv][r16][g4 * 8];
    const s16x8 ap1 = *(const s16x8*)&Ps[wv][16 + r16][g4 * 8];
    #pragma unroll
    for (int nf = 0; nf < 8; nf++){
      const int dh = nf * 16 + r16;
      const s16x8 bv = *(const s16x8*)&Vs[c][dh * 32 + ((g4 ^ ((dh >> 1) & 3)) << 3)];
      oacc[0][nf] = __builtin_amdgcn_mfma_f32_16x16x32_bf16(ap0, bv, oacc[0][nf], 0, 0, 0);
      oacc[1][nf] = __builtin_amdgcn_mfma_f32_16x16x32_bf16(ap1, bv, oacc[1][nf], 0, 0, 0);
    }
    __builtin_amdgcn_s_barrier();
  }
  #pragma unroll
  for (int mi = 0; mi < 2; mi++){
    #pragma unroll
    for (int r = 0; r < 4; r++){
      const float inv = 1.0f / lrun[mi][r];
      const size_t rowbase = head + (size_t)(q0 + mi * 16 + g4 * 4 + r) * 128;
      #pragma unroll
      for (int nf = 0; nf < 8; nf++){
        o[rowbase + nf * 16 + r16] = f2bf(oacc[mi][nf][r] * inv);
      }
    }
  }
}

// ------------------- per-channel contrastive (gram+norms+lse fused)
__launch_bounds__(256)
__global__ void k_contrast(const float* __restrict__ seq, const float* __restrict__ lab,
                           double* __restrict__ accs){
  __shared__ float ss[8][32][8];
  __shared__ float ls[8][32][8];
  __shared__ float rsl[32][8];
  __shared__ float redM[4], redC[4];
  const int tid = threadIdx.x, lane = tid & 63, wv = tid >> 6;
  const int i = tid >> 3, dd = tid & 7;
  const int d = blockIdx.x * 8 + dd;
  float accM[32], accC[32];
  #pragma unroll
  for (int j = 0; j < 32; j++){ accM[j] = 0.f; accC[j] = 0.f; }
  float accS = 0.f, accL = 0.f;
  for (int l0 = 0; l0 < 256; l0 += 8){
    #pragma unroll
    for (int li = 0; li < 8; li++){
      ss[li][i][dd] = seq[((size_t)(i * 256 + l0 + li)) * 2048 + d];
      ls[li][i][dd] = lab[((size_t)(i * 256 + l0 + li)) * 2048 + d];
    }
    __syncthreads();
    #pragma unroll
    for (int li = 0; li < 8; li++){
      const float sv = ss[li][i][dd];
      const float lv = ls[li][i][dd];
      accS += sv * sv; accL += lv * lv;
      #pragma unroll
      for (int j = 0; j < 32; j++){
        const float lj = ls[li][j][dd];
        accM[j] += sv * lj;
        accC[j] += lv * lj;
      }
    }
    __syncthreads();
  }
  rsl[i][dd] = rsqrtf(accL);
  __syncthreads();
  const float rs1 = rsqrtf(accS);
  const float rso = rsl[i][dd];
  float mx = -1e30f, diag = 0.f;
  #pragma unroll
  for (int j = 0; j < 32; j++){
    const float lg = accM[j] * rs1 * rsl[j][dd] * TAU_INV;
    mx = fmaxf(mx, lg);
    if (j == i) diag = lg;
  }
  float sum = 0.f;
  #pragma unroll
  for (int j = 0; j < 32; j++){
    const float lg = accM[j] * rs1 * rsl[j][dd] * TAU_INV;
    sum += exp2f((lg - mx) * LOG2E);
  }
  const float lossM = mx + logf(sum) - diag;
  mx = -1e30f; diag = 0.f;
  #pragma unroll
  for (int j = 0; j < 32; j++){
    const float lg = accC[j] * rso * rsl[j][dd] * TAU_INV;
    mx = fmaxf(mx, lg);
    if (j == i) diag = lg;
  }
  sum = 0.f;
  #pragma unroll
  for (int j = 0; j < 32; j++){
    const float lg = accC[j] * rso * rsl[j][dd] * TAU_INV;
    sum += exp2f((lg - mx) * LOG2E);
  }
  const float lossC = mx + logf(sum) - diag;

  float vM = lossM, vC = lossC;
  #pragma unroll
  for (int s = 32; s >= 1; s >>= 1){ vM += __shfl_xor(vM, s); vC += __shfl_xor(vC, s); }
  if (lane == 0){ redM[wv] = vM; redC[wv] = vC; }
  __syncthreads();
  if (tid == 0){
    atomicAdd(&accs[2], (double)(redM[0] + redM[1] + redM[2] + redM[3]));
    atomicAdd(&accs[3], (double)(redC[0] + redC[1] + redC[2] + redC[3]));
  }
}

// ---------------------------------------------------------------- finalize
__global__ void k_final(const float* __restrict__ scal, const double* __restrict__ accs,
                        float* __restrict__ out){
  if (threadIdx.x == 0){
    const double inv = 1.0 / ((double)M_ * (double)D_);
    double v = accs[1] * inv
             + (double)scal[64] * accs[0] * inv
             + accs[2] / 65536.0
             + accs[3] / 65536.0;
    out[0] = (float)v;
  }
}

extern "C" void kernel_launch(void* const* d_in, const int* in_sizes, int n_in,
                              void* d_out, int out_size, void* d_ws, size_t ws_size,
                              hipStream_t stream){
  const float* seq   = (const float*)d_in[0];
  const float* lab   = (const float*)d_in[1];
  const float* noise = (const float*)d_in[2];
  const float* sac   = (const float*)d_in[3];
  const float* s1m   = (const float*)d_in[4];
  const float* wq    = (const float*)d_in[5];
  const float* wk    = (const float*)d_in[6];
  const float* wvp   = (const float*)d_in[7];
  const float* wo    = (const float*)d_in[8];
  const int*   ts    = (const int*)d_in[9];

  char* ws = (char*)d_ws;
  float*    scal = (float*)ws;
  double*   accs = (double*)(ws + 512);
  uint16_t* wqkv = (uint16_t*)(ws + 1024);
  uint16_t* wo_t = wqkv + (size_t)NQKV_ * D_;
  uint16_t* xt   = wo_t + (size_t)D_ * D_;
  uint16_t* qb   = xt + (size_t)M_ * D_;
  uint16_t* kb   = qb + (size_t)M_ * D_;
  uint16_t* vtb  = kb + (size_t)M_ * D_;
  float* out = (float*)d_out;

  k_prep<<<1, 128, 0, stream>>>(sac, s1m, ts, scal, accs);
  k_convw<<<dim3(32, 32, 4), 256, 0, stream>>>(wq, wk, wvp, wo, wqkv, wo_t);
  k_xt<<<16384, 256, 0, stream>>>(seq, lab, noise, scal, accs, xt);
  k_gemm256<0><<<1536, 512, 0, stream>>>(xt, wqkv, qb, kb, vtb, nullptr, nullptr, nullptr);
  k_attn<<<2048, 256, 0, stream>>>(qb, kb, vtb, xt);
  k_gemm256<1><<<512, 512, 0, stream>>>(xt, wo_t, nullptr, nullptr, nullptr, seq, lab, accs);
  k_contrast<<<256, 256, 0, stream>>>(seq, lab, accs);
  k_final<<<1, 64, 0, stream>>>(scal, accs, out);
}